// Round 1
// baseline (288.460 us; speedup 1.0000x reference)
//
#include <hip/hip_runtime.h>
#include <math.h>

#define D 4096
#define NT 256
#define PER 16           // D / NT
#define EPS 1e-5f
#define EPS_SQRT 3.16227766016837933e-3f

__global__ __launch_bounds__(NT) void lnn_kernel(const float* __restrict__ x,
                                                 const float* __restrict__ w,
                                                 const float* __restrict__ b,
                                                 float* __restrict__ out) {
    const int row = blockIdx.x;
    const int tid = threadIdx.x;
    const float* xr = x + (size_t)row * D;
    float* orow = out + (size_t)row * D;

    __shared__ float red[4][8];  // 4 waves x up to 5 partials

    // ---- load 16 floats/thread as 4x float4, coalesced ----
    float v[PER];
    const float4* x4 = (const float4*)xr;
#pragma unroll
    for (int c = 0; c < 4; ++c) {
        float4 f = x4[c * NT + tid];
        v[c*4+0] = f.x; v[c*4+1] = f.y; v[c*4+2] = f.z; v[c*4+3] = f.w;
    }

    // ---- pass 1: mean / var ----
    float s = 0.f, s2 = 0.f;
#pragma unroll
    for (int i = 0; i < PER; ++i) { s += v[i]; s2 = fmaf(v[i], v[i], s2); }
#pragma unroll
    for (int o = 32; o > 0; o >>= 1) {
        s  += __shfl_down(s,  o, 64);
        s2 += __shfl_down(s2, o, 64);
    }
    const int wave = tid >> 6;
    if ((tid & 63) == 0) { red[wave][0] = s; red[wave][1] = s2; }
    __syncthreads();
    s  = red[0][0] + red[1][0] + red[2][0] + red[3][0];
    s2 = red[0][1] + red[1][1] + red[2][1] + red[3][1];
    const float inv_d = 1.f / (float)D;
    const float mean = s * inv_d;
    const float var  = s2 * inv_d - mean * mean;
    const float rstd = rsqrtf(var + EPS);

    // ---- pass 2: xs, l1p, 5 row-sums (all in registers) ----
    float lp[PER];
    float s1 = 0.f, sxd = 0.f, sd = 0.f, sd2 = 0.f, sxd2 = 0.f;
#pragma unroll
    for (int i = 0; i < PER; ++i) {
        float xs = (v[i] - mean) * rstd;
        v[i] = xs;
        float ab = fabsf(xs);
        float sg = (xs >= 0.f) ? 1.f : -1.f;   // sign with 0 -> +1
        float l  = log1pf(ab);
        lp[i] = l;
        float onea = 1.f + ab;
        float dd = onea * l - ab;              // d = (1+|xs|)l1p - |xs|
        s1   += sg * l;                        // sum sign*l1p
        sxd   = fmaf(xs, dd, sxd);             // sum xs*d
        sd   += dd;                            // sum d
        sd2   = fmaf(dd, dd, sd2);             // sum d^2
        float p1 = onea * l * l - 2.f * dd;    // (1+|xs|)l1p^2 - 2d
        sxd2  = fmaf(ab, p1, sxd2);            // sum xs*d2 = |xs|*p1
    }
#pragma unroll
    for (int o = 32; o > 0; o >>= 1) {
        s1   += __shfl_down(s1,   o, 64);
        sxd  += __shfl_down(sxd,  o, 64);
        sd   += __shfl_down(sd,   o, 64);
        sd2  += __shfl_down(sd2,  o, 64);
        sxd2 += __shfl_down(sxd2, o, 64);
    }
    __syncthreads();   // everyone done reading pass-1 partials
    if ((tid & 63) == 0) {
        red[wave][0] = s1; red[wave][1] = sxd; red[wave][2] = sd;
        red[wave][3] = sd2; red[wave][4] = sxd2;
    }
    __syncthreads();
    s1   = red[0][0] + red[1][0] + red[2][0] + red[3][0];
    sxd  = red[0][1] + red[1][1] + red[2][1] + red[3][1];
    sd   = red[0][2] + red[1][2] + red[2][2] + red[3][2];
    sd2  = red[0][3] + red[1][3] + red[2][3] + red[3][3];
    sxd2 = red[0][4] + red[1][4] + red[2][4] + red[3][4];

    // ---- row scalars (computed redundantly by every thread) ----
    const float dvar  = 2.f * sxd * inv_d;
    const float g1    = 0.5f * dvar - s1 * inv_d;
    const float dmean = sd * inv_d;
    const float vard  = sd2 * inv_d - dmean * dmean;   // mean((d-dmean)^2)
    const float d2var = 2.f * (sxd2 * inv_d + vard);
    const float g2    = -0.5f * dvar * dvar + 0.5f * d2var;
    const float lm    = 1.f - g1 / (g2 + EPS_SQRT);

    // eta/exponent take only two values per row (x_sign = +-1)
    const float eta_p = lm;
    const float eta_n = 2.f - lm;
    const float ep = eta_p + ((eta_p >= 0.f) ? EPS_SQRT : -EPS_SQRT);
    const float en = eta_n + ((eta_n >= 0.f) ? EPS_SQRT : -EPS_SQRT);
    const bool  mp = fabsf(eta_p) <= EPS_SQRT;
    const bool  mn = fabsf(eta_n) <= EPS_SQRT;
    const float rep = 1.f / ep;
    const float ren = 1.f / en;

    // ---- pass 3: transform + affine, write out ----
    const float4* w4 = (const float4*)w;
    const float4* b4 = (const float4*)b;
#pragma unroll
    for (int c = 0; c < 4; ++c) {
        float4 wf = w4[c * NT + tid];
        float4 bf = b4[c * NT + tid];
        float wa[4] = {wf.x, wf.y, wf.z, wf.w};
        float ba[4] = {bf.x, bf.y, bf.z, bf.w};
        float oa[4];
#pragma unroll
        for (int j = 0; j < 4; ++j) {
            int i = c*4 + j;
            float xs = v[i];
            bool pos = (xs >= 0.f);
            float sg = pos ? 1.f : -1.f;
            float l  = lp[i];
            float e  = pos ? ep : en;
            float re = pos ? rep : ren;
            bool  m  = pos ? mp : mn;
            float tr1 = sg * re * expm1f(e * l);   // (sign/exp)*((1+|xs|)^exp - 1)
            float tr2 = sg * l;
            float tr = m ? tr2 : tr1;
            oa[j] = fmaf(tr, wa[j], ba[j]);
        }
        float4 o = {oa[0], oa[1], oa[2], oa[3]};
        ((float4*)orow)[c * NT + tid] = o;
    }
}

extern "C" void kernel_launch(void* const* d_in, const int* in_sizes, int n_in,
                              void* d_out, int out_size, void* d_ws, size_t ws_size,
                              hipStream_t stream) {
    const float* x = (const float*)d_in[0];
    const float* w = (const float*)d_in[1];
    const float* b = (const float*)d_in[2];
    float* out = (float*)d_out;
    const int rows = in_sizes[0] / D;   // 8192
    lnn_kernel<<<dim3(rows), dim3(NT), 0, stream>>>(x, w, b, out);
}

// Round 2
// 227.503 us; speedup vs baseline: 1.2679x; 1.2679x over previous
//
#include <hip/hip_runtime.h>
#include <math.h>

#define D 4096
#define NT 256
#define PER 16           // D / NT
#define EPS 1e-5f
#define EPS_SQRT 3.16227766016837933e-3f
#define LN2 0.69314718055994531f

__global__ __launch_bounds__(NT) void lnn_kernel(const float* __restrict__ x,
                                                 const float* __restrict__ w,
                                                 const float* __restrict__ b,
                                                 float* __restrict__ out) {
    const int row = blockIdx.x;
    const int tid = threadIdx.x;
    const float* xr = x + (size_t)row * D;
    float* orow = out + (size_t)row * D;

    __shared__ float red[4][8];  // 4 waves x up to 5 partials

    // ---- load 16 floats/thread as 4x float4, coalesced ----
    float v[PER];
    const float4* x4 = (const float4*)xr;
#pragma unroll
    for (int c = 0; c < 4; ++c) {
        float4 f = x4[c * NT + tid];
        v[c*4+0] = f.x; v[c*4+1] = f.y; v[c*4+2] = f.z; v[c*4+3] = f.w;
    }

    // ---- pass 1: mean / var ----
    float s = 0.f, s2 = 0.f;
#pragma unroll
    for (int i = 0; i < PER; ++i) { s += v[i]; s2 = fmaf(v[i], v[i], s2); }
#pragma unroll
    for (int o = 32; o > 0; o >>= 1) {
        s  += __shfl_down(s,  o, 64);
        s2 += __shfl_down(s2, o, 64);
    }
    const int wave = tid >> 6;
    if ((tid & 63) == 0) { red[wave][0] = s; red[wave][1] = s2; }
    __syncthreads();
    s  = red[0][0] + red[1][0] + red[2][0] + red[3][0];
    s2 = red[0][1] + red[1][1] + red[2][1] + red[3][1];
    const float inv_d = 1.f / (float)D;
    const float mean = s * inv_d;
    const float var  = s2 * inv_d - mean * mean;
    const float rstd = rsqrtf(var + EPS);

    // ---- pass 2: xs, L2 = log2(1+|xs|), 5 row-sums (all in registers) ----
    float lp[PER];   // log2-domain log1p
    float s1 = 0.f, sxd = 0.f, sd = 0.f, sd2 = 0.f, sxd2 = 0.f;
#pragma unroll
    for (int i = 0; i < PER; ++i) {
        float xs = (v[i] - mean) * rstd;
        v[i] = xs;
        float ab = fabsf(xs);
        float L2 = __builtin_amdgcn_logf(1.f + ab);  // v_log_f32: log2(1+|xs|)
        lp[i] = L2;
        float l  = L2 * LN2;                         // natural log1p
        float onea = 1.f + ab;
        float dd = fmaf(onea, l, -ab);               // d = (1+|xs|)l1p - |xs|
        s1   += copysignf(l, xs);                    // sum sign*l1p
        sxd   = fmaf(xs, dd, sxd);                   // sum xs*d
        sd   += dd;                                  // sum d
        sd2   = fmaf(dd, dd, sd2);                   // sum d^2
        float ll = l * l;
        float p1 = fmaf(onea, ll, -(dd + dd));       // (1+|xs|)l1p^2 - 2d
        sxd2  = fmaf(ab, p1, sxd2);                  // sum xs*d2 = |xs|*p1
    }
#pragma unroll
    for (int o = 32; o > 0; o >>= 1) {
        s1   += __shfl_down(s1,   o, 64);
        sxd  += __shfl_down(sxd,  o, 64);
        sd   += __shfl_down(sd,   o, 64);
        sd2  += __shfl_down(sd2,  o, 64);
        sxd2 += __shfl_down(sxd2, o, 64);
    }
    __syncthreads();   // everyone done reading pass-1 partials
    if ((tid & 63) == 0) {
        red[wave][0] = s1; red[wave][1] = sxd; red[wave][2] = sd;
        red[wave][3] = sd2; red[wave][4] = sxd2;
    }
    __syncthreads();
    s1   = red[0][0] + red[1][0] + red[2][0] + red[3][0];
    sxd  = red[0][1] + red[1][1] + red[2][1] + red[3][1];
    sd   = red[0][2] + red[1][2] + red[2][2] + red[3][2];
    sd2  = red[0][3] + red[1][3] + red[2][3] + red[3][3];
    sxd2 = red[0][4] + red[1][4] + red[2][4] + red[3][4];

    // ---- row scalars (computed redundantly by every thread) ----
    const float dvar  = 2.f * sxd * inv_d;
    const float g1    = 0.5f * dvar - s1 * inv_d;
    const float dmean = sd * inv_d;
    const float vard  = sd2 * inv_d - dmean * dmean;   // mean((d-dmean)^2)
    const float d2var = 2.f * (sxd2 * inv_d + vard);
    const float g2    = -0.5f * dvar * dvar + 0.5f * d2var;
    const float lm    = 1.f - g1 * __builtin_amdgcn_rcpf(g2 + EPS_SQRT);

    // eta/exponent take only two values per row (x_sign = +-1)
    const float eta_p = lm;
    const float eta_n = 2.f - lm;
    const float ep = eta_p + ((eta_p >= 0.f) ? EPS_SQRT : -EPS_SQRT);
    const float en = eta_n + ((eta_n >= 0.f) ? EPS_SQRT : -EPS_SQRT);
    const bool  mp = fabsf(eta_p) <= EPS_SQRT;
    const bool  mn = fabsf(eta_n) <= EPS_SQRT;
    // fold sign into the reciprocal: tr1 = (pos ? 1/ep : -1/en) * (exp2(e*L2)-1)
    const float rp =  __builtin_amdgcn_rcpf(ep);
    const float rn = -__builtin_amdgcn_rcpf(en);

    // ---- pass 3: transform + affine, write out ----
    const float4* w4 = (const float4*)w;
    const float4* b4 = (const float4*)b;
#pragma unroll
    for (int c = 0; c < 4; ++c) {
        float4 wf = w4[c * NT + tid];
        float4 bf = b4[c * NT + tid];
        float wa[4] = {wf.x, wf.y, wf.z, wf.w};
        float ba[4] = {bf.x, bf.y, bf.z, bf.w};
        float oa[4];
#pragma unroll
        for (int j = 0; j < 4; ++j) {
            int i = c*4 + j;
            float xs = v[i];
            bool pos = (xs >= 0.f);
            float L2 = lp[i];
            float e  = pos ? ep : en;
            float re = pos ? rp : rn;
            bool  m  = pos ? mp : mn;
            // expm1(e * l1p) = exp2(e * L2) - 1
            float em = __builtin_amdgcn_exp2f(e * L2) - 1.f;
            float tr1 = re * em;
            float tr2 = copysignf(L2 * LN2, xs);   // sign * l1p
            float tr = m ? tr2 : tr1;
            oa[j] = fmaf(tr, wa[j], ba[j]);
        }
        float4 o = {oa[0], oa[1], oa[2], oa[3]};
        ((float4*)orow)[c * NT + tid] = o;
    }
}

extern "C" void kernel_launch(void* const* d_in, const int* in_sizes, int n_in,
                              void* d_out, int out_size, void* d_ws, size_t ws_size,
                              hipStream_t stream) {
    const float* x = (const float*)d_in[0];
    const float* w = (const float*)d_in[1];
    const float* b = (const float*)d_in[2];
    float* out = (float*)d_out;
    const int rows = in_sizes[0] / D;   // 8192
    lnn_kernel<<<dim3(rows), dim3(NT), 0, stream>>>(x, w, b, out);
}